// Round 1
// baseline (406.934 us; speedup 1.0000x reference)
//
#include <hip/hip_runtime.h>

#define N_N 50000
#define N_E 800000
#define NG  128

typedef float4 f4;

// ---------------- CSR build ----------------
__global__ __launch_bounds__(256) void k_deg(const int* __restrict__ ei, int* __restrict__ deg){
  int e = blockIdx.x*256 + threadIdx.x;
  if (e < N_E) atomicAdd(&deg[ei[N_E + e]], 1);
}

__global__ __launch_bounds__(256) void k_dinv(const int* __restrict__ deg, float* __restrict__ dinv){
  int i = blockIdx.x*256 + threadIdx.x;
  if (i < N_N) dinv[i] = rsqrtf((float)(deg[i] + 1));   // +1 self-loop
}

__global__ __launch_bounds__(256) void k_scan1(const int* __restrict__ deg, int* __restrict__ offs, int* __restrict__ bsum){
  __shared__ int wsum[4];
  int i = blockIdx.x*256 + threadIdx.x;
  int v = (i < N_N) ? deg[i] : 0;
  int lane = threadIdx.x & 63, w = threadIdx.x >> 6;
  int x = v;
  #pragma unroll
  for (int d=1; d<64; d<<=1){ int y = __shfl_up(x, d, 64); if (lane >= d) x += y; }
  if (lane == 63) wsum[w] = x;
  __syncthreads();
  if (threadIdx.x == 0){ int s=0; for (int j=0;j<4;j++){ int t=wsum[j]; wsum[j]=s; s+=t; } }
  __syncthreads();
  int excl = x - v + wsum[w];
  if (i < N_N) offs[i] = excl;
  if (threadIdx.x == 255) bsum[blockIdx.x] = excl + v;
}

__global__ __launch_bounds__(256) void k_scan2(const int* __restrict__ bsum, int* __restrict__ bofs, int nb){
  __shared__ int wsum[4];
  int t = threadIdx.x;
  int v = (t < nb) ? bsum[t] : 0;
  int lane = t & 63, w = t >> 6;
  int x = v;
  #pragma unroll
  for (int d=1; d<64; d<<=1){ int y = __shfl_up(x, d, 64); if (lane >= d) x += y; }
  if (lane == 63) wsum[w] = x;
  __syncthreads();
  if (t == 0){ int s=0; for (int j=0;j<4;j++){ int tt=wsum[j]; wsum[j]=s; s+=tt; } }
  __syncthreads();
  int excl = x - v + wsum[w];
  if (t < nb) bofs[t] = excl;
}

__global__ __launch_bounds__(256) void k_scan3(int* __restrict__ offs, int* __restrict__ curs, const int* __restrict__ bofs){
  int i = blockIdx.x*256 + threadIdx.x;
  if (i < N_N){
    int o = offs[i] + bofs[blockIdx.x];
    offs[i] = o;
    curs[i] = o;
  }
  if (i == 0) offs[N_N] = N_E;
}

__global__ __launch_bounds__(256) void k_place(const int* __restrict__ ei, int* __restrict__ curs, int* __restrict__ ssrc){
  int e = blockIdx.x*256 + threadIdx.x;
  if (e < N_E){
    int d = ei[N_E + e];
    int pos = atomicAdd(&curs[d], 1);
    ssrc[pos] = ei[e];
  }
}

// ---------------- fused add + preprocess MLP (64->128, relu) ----------------
__global__ __launch_bounds__(256) void k_pre(const float* __restrict__ emb, const float* __restrict__ pose,
    const float* __restrict__ W, const float* __restrict__ bias, float* __restrict__ out){
  __shared__ float As[64*64];
  __shared__ float Bs[64*128];
  int row0 = blockIdx.x*64, tid = threadIdx.x;
  for (int j=tid; j<2048; j+=256) ((f4*)Bs)[j] = ((const f4*)W)[j];
  for (int j=tid; j<1024; j+=256){
    int r = j>>4, c4 = j&15;
    int gr = row0 + r;
    f4 a = {0.f,0.f,0.f,0.f};
    if (gr < N_N){
      f4 e0 = ((const f4*)emb)[gr*16 + c4];
      f4 p0 = ((const f4*)pose)[gr*16 + c4];
      a.x = e0.x+p0.x; a.y = e0.y+p0.y; a.z = e0.z+p0.z; a.w = e0.w+p0.w;
    }
    ((f4*)As)[j] = a;
  }
  __syncthreads();
  int cg = tid&31, rg = tid>>5;
  float acc[8][4] = {};
  for (int k=0;k<64;k++){
    f4 b = ((f4*)Bs)[k*32 + cg];
    #pragma unroll
    for (int i=0;i<8;i++){
      float a = As[(rg*8+i)*64 + k];
      acc[i][0] = fmaf(a,b.x,acc[i][0]); acc[i][1] = fmaf(a,b.y,acc[i][1]);
      acc[i][2] = fmaf(a,b.z,acc[i][2]); acc[i][3] = fmaf(a,b.w,acc[i][3]);
    }
  }
  f4 bb = ((const f4*)bias)[cg];
  for (int i=0;i<8;i++){
    int gr = row0 + rg*8 + i;
    if (gr < N_N){
      f4 o;
      o.x = fmaxf(acc[i][0]+bb.x, 0.f); o.y = fmaxf(acc[i][1]+bb.y, 0.f);
      o.z = fmaxf(acc[i][2]+bb.z, 0.f); o.w = fmaxf(acc[i][3]+bb.w, 0.f);
      ((f4*)out)[gr*32 + cg] = o;
    }
  }
}

// ---------------- GEMM 128x128 + row scale (hs = (A@W) * dinv[row]) ----------------
__global__ __launch_bounds__(256) void k_gemm_scale(const float* __restrict__ A, const float* __restrict__ W,
    const float* __restrict__ scale, float* __restrict__ out){
  __shared__ float As[64*64];
  __shared__ float Bs[64*128];
  int row0 = blockIdx.x*64, tid = threadIdx.x;
  int cg = tid&31, rg = tid>>5;
  float acc[8][4] = {};
  for (int kk=0; kk<128; kk+=64){
    __syncthreads();
    for (int j=tid; j<2048; j+=256) ((f4*)Bs)[j] = ((const f4*)W)[kk*32 + j];
    for (int j=tid; j<1024; j+=256){
      int r=j>>4, c4=j&15, gr=row0+r;
      f4 a = {0.f,0.f,0.f,0.f};
      if (gr < N_N) a = ((const f4*)A)[gr*32 + (kk>>2) + c4];
      ((f4*)As)[j] = a;
    }
    __syncthreads();
    for (int k=0;k<64;k++){
      f4 b = ((f4*)Bs)[k*32+cg];
      #pragma unroll
      for (int i=0;i<8;i++){
        float a = As[(rg*8+i)*64+k];
        acc[i][0]=fmaf(a,b.x,acc[i][0]); acc[i][1]=fmaf(a,b.y,acc[i][1]);
        acc[i][2]=fmaf(a,b.z,acc[i][2]); acc[i][3]=fmaf(a,b.w,acc[i][3]);
      }
    }
  }
  for (int i=0;i<8;i++){
    int gr = row0+rg*8+i;
    if (gr < N_N){
      float s = scale[gr];
      f4 o = {acc[i][0]*s, acc[i][1]*s, acc[i][2]*s, acc[i][3]*s};
      ((f4*)out)[gr*32+cg] = o;
    }
  }
}

// ---------------- edge aggregation: out[v] = relu(dinv[v]*(hs[v] + sum hs[src]) + b) ----------------
__global__ __launch_bounds__(256) void k_agg(const float* __restrict__ hs, const int* __restrict__ offs,
    const int* __restrict__ ssrc, const float* __restrict__ dinv, const float* __restrict__ bias,
    float* __restrict__ out){
  int v = blockIdx.x*4 + (threadIdx.x>>6);
  int l = threadIdx.x & 63;
  const float2* h2 = (const float2*)hs;
  float2 acc = h2[v*64 + l];          // self-loop term hs[v]
  int s = offs[v], e = offs[v+1];
  for (int j=s; j<e; j++){
    int u = ssrc[j];
    float2 m = h2[u*64 + l];
    acc.x += m.x; acc.y += m.y;
  }
  float dv = dinv[v];
  float2 bb = ((const float2*)bias)[l];
  float2 o;
  o.x = fmaxf(fmaf(dv, acc.x, bb.x), 0.f);
  o.y = fmaxf(fmaf(dv, acc.y, bb.y), 0.f);
  ((float2*)out)[v*64 + l] = o;
}

// ---------------- mean pool over sorted batch ----------------
__global__ __launch_bounds__(128) void k_pool(const float* __restrict__ x, const int* __restrict__ batch,
    float* __restrict__ gsum, float* __restrict__ gcnt){
  int c = threadIdx.x;
  int n0 = blockIdx.x*128;
  int n1 = n0 + 128; if (n1 > N_N) n1 = N_N;
  int cur = batch[n0];
  float acc = 0.f, cnt = 0.f;
  for (int i=n0; i<n1; i++){
    int b = batch[i];
    if (b != cur){
      atomicAdd(&gsum[cur*128+c], acc);
      if (c == 0) atomicAdd(&gcnt[cur], cnt);
      acc = 0.f; cnt = 0.f; cur = b;
    }
    acc += x[i*128+c];
    cnt += 1.f;
  }
  atomicAdd(&gsum[cur*128+c], acc);
  if (c == 0) atomicAdd(&gcnt[cur], cnt);
}

// ---------------- head MLP (128->64->32, relu both) ----------------
__global__ __launch_bounds__(64) void k_head(const float* __restrict__ gsum, const float* __restrict__ gcnt,
    const float* __restrict__ W1, const float* __restrict__ b1,
    const float* __restrict__ W2, const float* __restrict__ b2, float* __restrict__ out){
  __shared__ float pooled[128];
  __shared__ float h1[64];
  int g = blockIdx.x, t = threadIdx.x;
  float cnt = fmaxf(gcnt[g], 1.f);
  pooled[t]      = gsum[g*128 + t] / cnt;
  pooled[t + 64] = gsum[g*128 + 64 + t] / cnt;
  __syncthreads();
  float a = b1[t];
  for (int k=0; k<128; k++) a = fmaf(pooled[k], W1[k*64 + t], a);
  h1[t] = fmaxf(a, 0.f);
  __syncthreads();
  if (t < 32){
    float o = b2[t];
    for (int k=0; k<64; k++) o = fmaf(h1[k], W2[k*32 + t], o);
    out[g*32 + t] = fmaxf(o, 0.f);
  }
}

extern "C" void kernel_launch(void* const* d_in, const int* in_sizes, int n_in,
                              void* d_out, int out_size, void* d_ws, size_t ws_size,
                              hipStream_t stream){
  const float* emb  = (const float*)d_in[0];
  const float* pose = (const float*)d_in[1];
  const int*   ei   = (const int*)d_in[2];
  const int*   batch= (const int*)d_in[3];
  const float* Wpre = (const float*)d_in[4];
  const float* bpre = (const float*)d_in[5];
  const float* Wg1  = (const float*)d_in[6];
  const float* bg1  = (const float*)d_in[7];
  const float* Wg2  = (const float*)d_in[8];
  const float* bg2  = (const float*)d_in[9];
  const float* Wh1  = (const float*)d_in[10];
  const float* bh1  = (const float*)d_in[11];
  const float* Wh2  = (const float*)d_in[12];
  const float* bh2  = (const float*)d_in[13];
  float* out = (float*)d_out;

  char* ws = (char*)d_ws;
  float* buf0 = (float*)(ws + 0);          // 25,600,000 B
  float* buf1 = (float*)(ws + 25600000);   // 25,600,000 B
  int*   deg  = (int*)  (ws + 51200000);   // 200,000 B
  float* dinv = (float*)(ws + 51400000);   // 200,000 B
  int*   offs = (int*)  (ws + 51600000);   // 200,004 B (pad to 200,192)
  int*   curs = (int*)  (ws + 51800192);   // 200,000 B
  int*   ssrc = (int*)  (ws + 52000256);   // 3,200,000 B
  int*   bsum = (int*)  (ws + 55200256);   // 1,024 B
  int*   bofs = (int*)  (ws + 55201280);   // 1,024 B
  float* gsum = (float*)(ws + 55202304);   // 65,536 B
  float* gcnt = (float*)(ws + 55267840);   // 512 B

  hipMemsetAsync(deg, 0, N_N*sizeof(int), stream);
  hipMemsetAsync(gsum, 0, (NG*128 + NG)*sizeof(float), stream);  // gsum + gcnt contiguous

  const int NB = (N_N + 255)/256;  // 196

  k_deg  <<<(N_E+255)/256, 256, 0, stream>>>(ei, deg);
  k_dinv <<<NB, 256, 0, stream>>>(deg, dinv);
  k_scan1<<<NB, 256, 0, stream>>>(deg, offs, bsum);
  k_scan2<<<1, 256, 0, stream>>>(bsum, bofs, NB);
  k_scan3<<<NB, 256, 0, stream>>>(offs, curs, bofs);
  k_place<<<(N_E+255)/256, 256, 0, stream>>>(ei, curs, ssrc);

  k_pre<<<(N_N+63)/64, 256, 0, stream>>>(emb, pose, Wpre, bpre, buf0);            // x1 -> buf0

  k_gemm_scale<<<(N_N+63)/64, 256, 0, stream>>>(buf0, Wg1, dinv, buf1);           // hs1 -> buf1
  k_agg<<<N_N/4, 256, 0, stream>>>(buf1, offs, ssrc, dinv, bg1, buf0);            // x2 -> buf0

  k_gemm_scale<<<(N_N+63)/64, 256, 0, stream>>>(buf0, Wg2, dinv, buf1);           // hs2 -> buf1
  k_agg<<<N_N/4, 256, 0, stream>>>(buf1, offs, ssrc, dinv, bg2, buf0);            // x3 -> buf0

  k_pool<<<(N_N+127)/128, 128, 0, stream>>>(buf0, batch, gsum, gcnt);
  k_head<<<NG, 64, 0, stream>>>(gsum, gcnt, Wh1, bh1, Wh2, bh2, out);
}

// Round 2
// 263.174 us; speedup vs baseline: 1.5463x; 1.5463x over previous
//
#include <hip/hip_runtime.h>

#define N_N 50000
#define N_E 800000
#define NG  128

typedef float4 f4;
typedef __attribute__((ext_vector_type(8))) short bf16x8;
typedef __attribute__((ext_vector_type(4))) float f32x4;

__device__ __forceinline__ unsigned short f2b(float x){
  unsigned int u = __float_as_uint(x);
  u += 0x7fffu + ((u >> 16) & 1u);
  return (unsigned short)(u >> 16);
}
__device__ __forceinline__ float b2f(unsigned short h){
  return __uint_as_float(((unsigned int)h) << 16);
}
__device__ __forceinline__ float2 b2f2(unsigned int u){
  float2 r;
  r.x = __uint_as_float(u << 16);
  r.y = __uint_as_float(u & 0xffff0000u);
  return r;
}

// ---------------- CSR build ----------------
__global__ __launch_bounds__(256) void k_deg(const int* __restrict__ ei, int* __restrict__ deg){
  int e = blockIdx.x*256 + threadIdx.x;
  if (e < N_E) atomicAdd(&deg[ei[N_E + e]], 1);
}

__global__ __launch_bounds__(256) void k_dinv(const int* __restrict__ deg, float* __restrict__ dinv){
  int i = blockIdx.x*256 + threadIdx.x;
  if (i < N_N) dinv[i] = rsqrtf((float)(deg[i] + 1));   // +1 self-loop
}

__global__ __launch_bounds__(256) void k_scan1(const int* __restrict__ deg, int* __restrict__ offs, int* __restrict__ bsum){
  __shared__ int wsum[4];
  int i = blockIdx.x*256 + threadIdx.x;
  int v = (i < N_N) ? deg[i] : 0;
  int lane = threadIdx.x & 63, w = threadIdx.x >> 6;
  int x = v;
  #pragma unroll
  for (int d=1; d<64; d<<=1){ int y = __shfl_up(x, d, 64); if (lane >= d) x += y; }
  if (lane == 63) wsum[w] = x;
  __syncthreads();
  if (threadIdx.x == 0){ int s=0; for (int j=0;j<4;j++){ int t=wsum[j]; wsum[j]=s; s+=t; } }
  __syncthreads();
  int excl = x - v + wsum[w];
  if (i < N_N) offs[i] = excl;
  if (threadIdx.x == 255) bsum[blockIdx.x] = excl + v;
}

__global__ __launch_bounds__(256) void k_scan2(const int* __restrict__ bsum, int* __restrict__ bofs, int nb){
  __shared__ int wsum[4];
  int t = threadIdx.x;
  int v = (t < nb) ? bsum[t] : 0;
  int lane = t & 63, w = t >> 6;
  int x = v;
  #pragma unroll
  for (int d=1; d<64; d<<=1){ int y = __shfl_up(x, d, 64); if (lane >= d) x += y; }
  if (lane == 63) wsum[w] = x;
  __syncthreads();
  if (t == 0){ int s=0; for (int j=0;j<4;j++){ int tt=wsum[j]; wsum[j]=s; s+=tt; } }
  __syncthreads();
  int excl = x - v + wsum[w];
  if (t < nb) bofs[t] = excl;
}

__global__ __launch_bounds__(256) void k_scan3(int* __restrict__ offs, int* __restrict__ curs, const int* __restrict__ bofs){
  int i = blockIdx.x*256 + threadIdx.x;
  if (i < N_N){
    int o = offs[i] + bofs[blockIdx.x];
    offs[i] = o;
    curs[i] = o;
  }
  if (i == 0) offs[N_N] = N_E;
}

__global__ __launch_bounds__(256) void k_place(const int* __restrict__ ei, int* __restrict__ curs, int* __restrict__ ssrc){
  int e = blockIdx.x*256 + threadIdx.x;
  if (e < N_E){
    int d = ei[N_E + e];
    int pos = atomicAdd(&curs[d], 1);
    ssrc[pos] = ei[e];
  }
}

// ---------------- W (fp32 [k][n]) -> Wt (bf16 [n][k]) ----------------
__global__ __launch_bounds__(256) void k_wt(const float* __restrict__ W, unsigned short* __restrict__ Wt){
  int i = blockIdx.x*256 + threadIdx.x;   // 16384
  int k = i >> 7, n = i & 127;
  Wt[n*128 + k] = f2b(W[k*128 + n]);
}

// ---------------- fused add + preprocess MLP (64->128, relu), bf16 out ----------------
__global__ __launch_bounds__(256) void k_pre(const float* __restrict__ emb, const float* __restrict__ pose,
    const float* __restrict__ W, const float* __restrict__ bias, unsigned short* __restrict__ out){
  __shared__ float As[64*64];
  __shared__ float Bs[64*128];
  int row0 = blockIdx.x*64, tid = threadIdx.x;
  for (int j=tid; j<2048; j+=256) ((f4*)Bs)[j] = ((const f4*)W)[j];
  for (int j=tid; j<1024; j+=256){
    int r = j>>4, c4 = j&15;
    int gr = row0 + r;
    f4 a = {0.f,0.f,0.f,0.f};
    if (gr < N_N){
      f4 e0 = ((const f4*)emb)[gr*16 + c4];
      f4 p0 = ((const f4*)pose)[gr*16 + c4];
      a.x = e0.x+p0.x; a.y = e0.y+p0.y; a.z = e0.z+p0.z; a.w = e0.w+p0.w;
    }
    ((f4*)As)[j] = a;
  }
  __syncthreads();
  int cg = tid&31, rg = tid>>5;
  float acc[8][4] = {};
  for (int k=0;k<64;k++){
    f4 b = ((f4*)Bs)[k*32 + cg];
    #pragma unroll
    for (int i=0;i<8;i++){
      float a = As[(rg*8+i)*64 + k];
      acc[i][0] = fmaf(a,b.x,acc[i][0]); acc[i][1] = fmaf(a,b.y,acc[i][1]);
      acc[i][2] = fmaf(a,b.z,acc[i][2]); acc[i][3] = fmaf(a,b.w,acc[i][3]);
    }
  }
  f4 bb = ((const f4*)bias)[cg];
  for (int i=0;i<8;i++){
    int gr = row0 + rg*8 + i;
    if (gr < N_N){
      ushort4 o;
      o.x = f2b(fmaxf(acc[i][0]+bb.x, 0.f));
      o.y = f2b(fmaxf(acc[i][1]+bb.y, 0.f));
      o.z = f2b(fmaxf(acc[i][2]+bb.z, 0.f));
      o.w = f2b(fmaxf(acc[i][3]+bb.w, 0.f));
      *(ushort4*)&out[gr*128 + cg*4] = o;
    }
  }
}

// ---------------- MFMA GEMM: hs = (A @ W) * dinv[row], A bf16 [M][128], Wt bf16 [n][k] ----------------
// block: 4 waves x 32 rows = 128 rows; wave: 2 m-frags x 8 n-frags, K-loop of 4 (16x16x32)
__global__ __launch_bounds__(256) void k_gemm_mfma(const unsigned short* __restrict__ A,
    const unsigned short* __restrict__ Wt, const float* __restrict__ scale,
    unsigned short* __restrict__ out){
  __shared__ unsigned short Bs[128*128];   // 32 KB, XOR-swizzled [n][k] tiles of 8 bf16
  int tid = threadIdx.x;
  // stage Wt -> LDS with swizzle: 16B chunk c of row n stored at c ^ (n&7)
  for (int j=tid; j<2048; j+=256){
    int n = j >> 4, c = j & 15;
    ((bf16x8*)Bs)[(n<<4) | (c ^ (n&7))] = ((const bf16x8*)Wt)[j];
  }
  __syncthreads();
  int wid = tid >> 6, l = tid & 63;
  int row0 = blockIdx.x*128 + wid*32;
  int lr = l & 15, kg = l >> 4;
  int ra = row0 + lr;       if (ra > N_N-1) ra = N_N-1;
  int rb = row0 + 16 + lr;  if (rb > N_N-1) rb = N_N-1;
  f32x4 acc[2][8] = {};
  #pragma unroll
  for (int ks=0; ks<4; ks++){
    int k0 = ks*32 + kg*8;
    bf16x8 a0 = *(const bf16x8*)&A[ra*128 + k0];
    bf16x8 a1 = *(const bf16x8*)&A[rb*128 + k0];
    #pragma unroll
    for (int nf=0; nf<8; nf++){
      int n = nf*16 + lr;
      bf16x8 b = ((const bf16x8*)Bs)[(n<<4) | ((ks*4+kg) ^ (lr&7))];
      acc[0][nf] = __builtin_amdgcn_mfma_f32_16x16x32_bf16(a0, b, acc[0][nf], 0, 0, 0);
      acc[1][nf] = __builtin_amdgcn_mfma_f32_16x16x32_bf16(a1, b, acc[1][nf], 0, 0, 0);
    }
  }
  // C/D layout: col = lane&15, row = (lane>>4)*4 + reg
  #pragma unroll
  for (int mf=0; mf<2; mf++){
    #pragma unroll
    for (int r=0; r<4; r++){
      int R = row0 + mf*16 + (l>>4)*4 + r;
      if (R < N_N){
        float s = scale[R];
        #pragma unroll
        for (int nf=0; nf<8; nf++){
          out[R*128 + nf*16 + lr] = f2b(acc[mf][nf][r] * s);
        }
      }
    }
  }
}

// ---------------- edge aggregation: out[v] = relu(dinv[v]*(hs[v] + sum hs[src]) + b), bf16 ----------------
__global__ __launch_bounds__(256) void k_agg(const unsigned short* __restrict__ hs,
    const int* __restrict__ offs, const int* __restrict__ ssrc, const float* __restrict__ dinv,
    const float* __restrict__ bias, unsigned short* __restrict__ out){
  int v = blockIdx.x*4 + (threadIdx.x>>6);
  int l = threadIdx.x & 63;
  const unsigned int* h2 = (const unsigned int*)hs;   // 2 bf16 per uint
  float2 acc = b2f2(h2[(v<<6) + l]);                  // self-loop term hs[v]
  int s = offs[v], e = offs[v+1];
  int j = s;
  for (; j+4 <= e; j+=4){
    int u0 = ssrc[j], u1 = ssrc[j+1], u2 = ssrc[j+2], u3 = ssrc[j+3];
    unsigned int m0 = h2[(u0<<6)+l];
    unsigned int m1 = h2[(u1<<6)+l];
    unsigned int m2 = h2[(u2<<6)+l];
    unsigned int m3 = h2[(u3<<6)+l];
    float2 f0 = b2f2(m0), f1 = b2f2(m1), f2 = b2f2(m2), f3 = b2f2(m3);
    acc.x += (f0.x + f1.x) + (f2.x + f3.x);
    acc.y += (f0.y + f1.y) + (f2.y + f3.y);
  }
  for (; j<e; j++){
    float2 m = b2f2(h2[(ssrc[j]<<6)+l]);
    acc.x += m.x; acc.y += m.y;
  }
  float dv = dinv[v];
  float2 bb = ((const float2*)bias)[l];
  unsigned int o = (unsigned int)f2b(fmaxf(fmaf(dv, acc.x, bb.x), 0.f))
                 | ((unsigned int)f2b(fmaxf(fmaf(dv, acc.y, bb.y), 0.f)) << 16);
  ((unsigned int*)out)[(v<<6) + l] = o;
}

// ---------------- mean pool over sorted batch (bf16 in) ----------------
__global__ __launch_bounds__(128) void k_pool(const unsigned short* __restrict__ x, const int* __restrict__ batch,
    float* __restrict__ gsum, float* __restrict__ gcnt){
  int c = threadIdx.x;
  int n0 = blockIdx.x*128;
  int n1 = n0 + 128; if (n1 > N_N) n1 = N_N;
  int cur = batch[n0];
  float acc = 0.f, cnt = 0.f;
  for (int i=n0; i<n1; i++){
    int b = batch[i];
    if (b != cur){
      atomicAdd(&gsum[cur*128+c], acc);
      if (c == 0) atomicAdd(&gcnt[cur], cnt);
      acc = 0.f; cnt = 0.f; cur = b;
    }
    acc += b2f(x[i*128+c]);
    cnt += 1.f;
  }
  atomicAdd(&gsum[cur*128+c], acc);
  if (c == 0) atomicAdd(&gcnt[cur], cnt);
}

// ---------------- head MLP (128->64->32, relu both) ----------------
__global__ __launch_bounds__(64) void k_head(const float* __restrict__ gsum, const float* __restrict__ gcnt,
    const float* __restrict__ W1, const float* __restrict__ b1,
    const float* __restrict__ W2, const float* __restrict__ b2, float* __restrict__ out){
  __shared__ float pooled[128];
  __shared__ float h1[64];
  int g = blockIdx.x, t = threadIdx.x;
  float cnt = fmaxf(gcnt[g], 1.f);
  pooled[t]      = gsum[g*128 + t] / cnt;
  pooled[t + 64] = gsum[g*128 + 64 + t] / cnt;
  __syncthreads();
  float a = b1[t];
  for (int k=0; k<128; k++) a = fmaf(pooled[k], W1[k*64 + t], a);
  h1[t] = fmaxf(a, 0.f);
  __syncthreads();
  if (t < 32){
    float o = b2[t];
    for (int k=0; k<64; k++) o = fmaf(h1[k], W2[k*32 + t], o);
    out[g*32 + t] = fmaxf(o, 0.f);
  }
}

extern "C" void kernel_launch(void* const* d_in, const int* in_sizes, int n_in,
                              void* d_out, int out_size, void* d_ws, size_t ws_size,
                              hipStream_t stream){
  const float* emb  = (const float*)d_in[0];
  const float* pose = (const float*)d_in[1];
  const int*   ei   = (const int*)d_in[2];
  const int*   batch= (const int*)d_in[3];
  const float* Wpre = (const float*)d_in[4];
  const float* bpre = (const float*)d_in[5];
  const float* Wg1  = (const float*)d_in[6];
  const float* bg1  = (const float*)d_in[7];
  const float* Wg2  = (const float*)d_in[8];
  const float* bg2  = (const float*)d_in[9];
  const float* Wh1  = (const float*)d_in[10];
  const float* bh1  = (const float*)d_in[11];
  const float* Wh2  = (const float*)d_in[12];
  const float* bh2  = (const float*)d_in[13];
  float* out = (float*)d_out;

  char* ws = (char*)d_ws;
  unsigned short* xb0 = (unsigned short*)(ws + 0);          // 12,800,000
  unsigned short* xb1 = (unsigned short*)(ws + 12800000);   // 12,800,000
  unsigned short* hb  = (unsigned short*)(ws + 25600000);   // 12,800,000
  unsigned short* Wt1 = (unsigned short*)(ws + 38400000);   // 32,768
  unsigned short* Wt2 = (unsigned short*)(ws + 38432768);   // 32,768
  int*   deg  = (int*)  (ws + 38465536);   // 200,000
  float* dinv = (float*)(ws + 38665536);   // 200,000
  int*   offs = (int*)  (ws + 38865536);   // 200,192 (N_N+1 ints, padded)
  int*   curs = (int*)  (ws + 39065728);   // 200,000
  int*   ssrc = (int*)  (ws + 39265728);   // 3,200,000
  int*   bsum = (int*)  (ws + 42465728);   // 1,024
  int*   bofs = (int*)  (ws + 42466752);   // 1,024
  float* gsum = (float*)(ws + 42467776);   // 65,536
  float* gcnt = (float*)(ws + 42533312);   // 512

  hipMemsetAsync(deg, 0, N_N*sizeof(int), stream);
  hipMemsetAsync(gsum, 0, (NG*128 + NG)*sizeof(float), stream);  // gsum + gcnt contiguous

  const int NB = (N_N + 255)/256;  // 196

  k_deg  <<<(N_E+255)/256, 256, 0, stream>>>(ei, deg);
  k_dinv <<<NB, 256, 0, stream>>>(deg, dinv);
  k_scan1<<<NB, 256, 0, stream>>>(deg, offs, bsum);
  k_scan2<<<1, 256, 0, stream>>>(bsum, bofs, NB);
  k_scan3<<<NB, 256, 0, stream>>>(offs, curs, bofs);
  k_place<<<(N_E+255)/256, 256, 0, stream>>>(ei, curs, ssrc);

  k_wt<<<64, 256, 0, stream>>>(Wg1, Wt1);
  k_wt<<<64, 256, 0, stream>>>(Wg2, Wt2);

  k_pre<<<(N_N+63)/64, 256, 0, stream>>>(emb, pose, Wpre, bpre, xb0);             // x1 -> xb0 (bf16)

  k_gemm_mfma<<<(N_N+127)/128, 256, 0, stream>>>(xb0, Wt1, dinv, hb);             // hs1 -> hb
  k_agg<<<N_N/4, 256, 0, stream>>>(hb, offs, ssrc, dinv, bg1, xb1);               // x2 -> xb1

  k_gemm_mfma<<<(N_N+127)/128, 256, 0, stream>>>(xb1, Wt2, dinv, hb);             // hs2 -> hb
  k_agg<<<N_N/4, 256, 0, stream>>>(hb, offs, ssrc, dinv, bg2, xb0);               // x3 -> xb0

  k_pool<<<(N_N+127)/128, 128, 0, stream>>>(xb0, batch, gsum, gcnt);
  k_head<<<NG, 64, 0, stream>>>(gsum, gcnt, Wh1, bh1, Wh2, bh2, out);
}

// Round 3
// 229.962 us; speedup vs baseline: 1.7696x; 1.1444x over previous
//
#include <hip/hip_runtime.h>

#define N_N 50000
#define N_E 800000
#define NG  128
#define NBKT 782          // ceil(50000/64) buckets of 64 nodes
#define CAP  1536         // slot capacity per bucket (mean 1023, std 32)

typedef float4 f4;
typedef __attribute__((ext_vector_type(8))) short bf16x8;
typedef __attribute__((ext_vector_type(4))) float f32x4;

__device__ __forceinline__ unsigned short f2b(float x){
  unsigned int u = __float_as_uint(x);
  u += 0x7fffu + ((u >> 16) & 1u);
  return (unsigned short)(u >> 16);
}
__device__ __forceinline__ float b2f(unsigned short h){
  return __uint_as_float(((unsigned int)h) << 16);
}
__device__ __forceinline__ float2 b2f2(unsigned int u){
  float2 r;
  r.x = __uint_as_float(u << 16);
  r.y = __uint_as_float(u & 0xffff0000u);
  return r;
}

// ---------------- bucket scatter: (src,dst) pairs into coarse buckets ----------------
__global__ __launch_bounds__(256) void k_bucket(const int* __restrict__ ei,
    int* __restrict__ bcnt, int2* __restrict__ pairs){
  int e = blockIdx.x*256 + threadIdx.x;
  if (e < N_E){
    int s = ei[e], d = ei[N_E + e];
    int b = d >> 6;
    int pos = atomicAdd(&bcnt[b*16], 1);      // 64B-strided cursors
    pairs[b*CAP + pos] = make_int2(s, d);
  }
}

// ---------------- per-bucket CSR finalize: hist -> scan -> place ----------------
__global__ __launch_bounds__(256) void k_csr(const int2* __restrict__ pairs,
    const int* __restrict__ bcnt, int2* __restrict__ sd, float* __restrict__ dinv,
    int* __restrict__ ssrc){
  __shared__ int hist[64];
  __shared__ int lcur[64];
  __shared__ int cnt_s;
  int b = blockIdx.x, t = threadIdx.x;
  if (t < 64) hist[t] = 0;
  if (t == 0) cnt_s = bcnt[b*16];
  __syncthreads();
  int cnt = cnt_s;
  const int2* P = pairs + b*CAP;
  for (int j=t; j<cnt; j+=256) atomicAdd(&hist[P[j].y & 63], 1);
  __syncthreads();
  if (t < 64){
    int v = hist[t];
    int x = v;
    #pragma unroll
    for (int dd=1; dd<64; dd<<=1){ int y = __shfl_up(x, dd, 64); if (t >= dd) x += y; }
    int excl = x - v;
    int node = (b<<6) + t;
    if (node < N_N){
      sd[node] = make_int2(b*CAP + excl, v);
      dinv[node] = rsqrtf((float)(v + 1));    // +1 self-loop
    }
    lcur[t] = b*CAP + excl;
  }
  __syncthreads();
  for (int j=t; j<cnt; j+=256){
    int2 p = P[j];
    int pos = atomicAdd(&lcur[p.y & 63], 1);
    ssrc[pos] = p.x;
  }
}

// ---------------- W (fp32 [k][n]) -> Wt (bf16 [n][k]) ----------------
__global__ __launch_bounds__(256) void k_wt(const float* __restrict__ W, unsigned short* __restrict__ Wt){
  int i = blockIdx.x*256 + threadIdx.x;   // 16384
  int k = i >> 7, n = i & 127;
  Wt[n*128 + k] = f2b(W[k*128 + n]);
}

// ---------------- fused add + preprocess MLP (64->128, relu), bf16 out ----------------
__global__ __launch_bounds__(256) void k_pre(const float* __restrict__ emb, const float* __restrict__ pose,
    const float* __restrict__ W, const float* __restrict__ bias, unsigned short* __restrict__ out){
  __shared__ float As[64*64];
  __shared__ float Bs[64*128];
  int row0 = blockIdx.x*64, tid = threadIdx.x;
  for (int j=tid; j<2048; j+=256) ((f4*)Bs)[j] = ((const f4*)W)[j];
  for (int j=tid; j<1024; j+=256){
    int r = j>>4, c4 = j&15;
    int gr = row0 + r;
    f4 a = {0.f,0.f,0.f,0.f};
    if (gr < N_N){
      f4 e0 = ((const f4*)emb)[gr*16 + c4];
      f4 p0 = ((const f4*)pose)[gr*16 + c4];
      a.x = e0.x+p0.x; a.y = e0.y+p0.y; a.z = e0.z+p0.z; a.w = e0.w+p0.w;
    }
    ((f4*)As)[j] = a;
  }
  __syncthreads();
  int cg = tid&31, rg = tid>>5;
  float acc[8][4] = {};
  for (int k=0;k<64;k++){
    f4 b = ((f4*)Bs)[k*32 + cg];
    #pragma unroll
    for (int i=0;i<8;i++){
      float a = As[(rg*8+i)*64 + k];
      acc[i][0] = fmaf(a,b.x,acc[i][0]); acc[i][1] = fmaf(a,b.y,acc[i][1]);
      acc[i][2] = fmaf(a,b.z,acc[i][2]); acc[i][3] = fmaf(a,b.w,acc[i][3]);
    }
  }
  f4 bb = ((const f4*)bias)[cg];
  for (int i=0;i<8;i++){
    int gr = row0 + rg*8 + i;
    if (gr < N_N){
      ushort4 o;
      o.x = f2b(fmaxf(acc[i][0]+bb.x, 0.f));
      o.y = f2b(fmaxf(acc[i][1]+bb.y, 0.f));
      o.z = f2b(fmaxf(acc[i][2]+bb.z, 0.f));
      o.w = f2b(fmaxf(acc[i][3]+bb.w, 0.f));
      *(ushort4*)&out[gr*128 + cg*4] = o;
    }
  }
}

// ---------------- MFMA GEMM: hs = (A @ W) * dinv[row], A bf16 [M][128], Wt bf16 [n][k] ----------------
__global__ __launch_bounds__(256) void k_gemm_mfma(const unsigned short* __restrict__ A,
    const unsigned short* __restrict__ Wt, const float* __restrict__ scale,
    unsigned short* __restrict__ out){
  __shared__ unsigned short Bs[128*128];   // 32 KB, XOR-swizzled [n][k] tiles of 8 bf16
  int tid = threadIdx.x;
  for (int j=tid; j<2048; j+=256){
    int n = j >> 4, c = j & 15;
    ((bf16x8*)Bs)[(n<<4) | (c ^ (n&7))] = ((const bf16x8*)Wt)[j];
  }
  __syncthreads();
  int wid = tid >> 6, l = tid & 63;
  int row0 = blockIdx.x*128 + wid*32;
  int lr = l & 15, kg = l >> 4;
  int ra = row0 + lr;       if (ra > N_N-1) ra = N_N-1;
  int rb = row0 + 16 + lr;  if (rb > N_N-1) rb = N_N-1;
  f32x4 acc[2][8] = {};
  #pragma unroll
  for (int ks=0; ks<4; ks++){
    int k0 = ks*32 + kg*8;
    bf16x8 a0 = *(const bf16x8*)&A[ra*128 + k0];
    bf16x8 a1 = *(const bf16x8*)&A[rb*128 + k0];
    #pragma unroll
    for (int nf=0; nf<8; nf++){
      int n = nf*16 + lr;
      bf16x8 b = ((const bf16x8*)Bs)[(n<<4) | ((ks*4+kg) ^ (lr&7))];
      acc[0][nf] = __builtin_amdgcn_mfma_f32_16x16x32_bf16(a0, b, acc[0][nf], 0, 0, 0);
      acc[1][nf] = __builtin_amdgcn_mfma_f32_16x16x32_bf16(a1, b, acc[1][nf], 0, 0, 0);
    }
  }
  #pragma unroll
  for (int mf=0; mf<2; mf++){
    #pragma unroll
    for (int r=0; r<4; r++){
      int R = row0 + mf*16 + (l>>4)*4 + r;
      if (R < N_N){
        float s = scale[R];
        #pragma unroll
        for (int nf=0; nf<8; nf++){
          out[R*128 + nf*16 + lr] = f2b(acc[mf][nf][r] * s);
        }
      }
    }
  }
}

// ---------------- edge aggregation: out[v] = relu(dinv[v]*(hs[v] + sum hs[src]) + b), bf16 ----------------
__global__ __launch_bounds__(256) void k_agg(const unsigned short* __restrict__ hs,
    const int2* __restrict__ sd, const int* __restrict__ ssrc, const float* __restrict__ dinv,
    const float* __restrict__ bias, unsigned short* __restrict__ out){
  int v = blockIdx.x*4 + (threadIdx.x>>6);
  int l = threadIdx.x & 63;
  const unsigned int* h2 = (const unsigned int*)hs;   // 2 bf16 per uint
  float2 acc = b2f2(h2[(v<<6) + l]);                  // self-loop term hs[v]
  int2 s_d = sd[v];
  int s = s_d.x, e = s + s_d.y;
  int j = s;
  for (; j+8 <= e; j+=8){
    int u0 = ssrc[j],   u1 = ssrc[j+1], u2 = ssrc[j+2], u3 = ssrc[j+3];
    int u4 = ssrc[j+4], u5 = ssrc[j+5], u6 = ssrc[j+6], u7 = ssrc[j+7];
    unsigned int m0 = h2[(u0<<6)+l], m1 = h2[(u1<<6)+l];
    unsigned int m2 = h2[(u2<<6)+l], m3 = h2[(u3<<6)+l];
    unsigned int m4 = h2[(u4<<6)+l], m5 = h2[(u5<<6)+l];
    unsigned int m6 = h2[(u6<<6)+l], m7 = h2[(u7<<6)+l];
    float2 f0=b2f2(m0), f1=b2f2(m1), f2=b2f2(m2), f3=b2f2(m3);
    float2 f4_=b2f2(m4), f5=b2f2(m5), f6=b2f2(m6), f7=b2f2(m7);
    acc.x += ((f0.x+f1.x)+(f2.x+f3.x)) + ((f4_.x+f5.x)+(f6.x+f7.x));
    acc.y += ((f0.y+f1.y)+(f2.y+f3.y)) + ((f4_.y+f5.y)+(f6.y+f7.y));
  }
  for (; j<e; j++){
    float2 m = b2f2(h2[(ssrc[j]<<6)+l]);
    acc.x += m.x; acc.y += m.y;
  }
  float dv = dinv[v];
  float2 bb = ((const float2*)bias)[l];
  unsigned int o = (unsigned int)f2b(fmaxf(fmaf(dv, acc.x, bb.x), 0.f))
                 | ((unsigned int)f2b(fmaxf(fmaf(dv, acc.y, bb.y), 0.f)) << 16);
  ((unsigned int*)out)[(v<<6) + l] = o;
}

// ---------------- mean pool over sorted batch (bf16 in) ----------------
__global__ __launch_bounds__(128) void k_pool(const unsigned short* __restrict__ x, const int* __restrict__ batch,
    float* __restrict__ gsum, float* __restrict__ gcnt){
  int c = threadIdx.x;
  int n0 = blockIdx.x*128;
  int n1 = n0 + 128; if (n1 > N_N) n1 = N_N;
  int cur = batch[n0];
  float acc = 0.f, cnt = 0.f;
  for (int i=n0; i<n1; i++){
    int b = batch[i];
    if (b != cur){
      atomicAdd(&gsum[cur*128+c], acc);
      if (c == 0) atomicAdd(&gcnt[cur], cnt);
      acc = 0.f; cnt = 0.f; cur = b;
    }
    acc += b2f(x[i*128+c]);
    cnt += 1.f;
  }
  atomicAdd(&gsum[cur*128+c], acc);
  if (c == 0) atomicAdd(&gcnt[cur], cnt);
}

// ---------------- head MLP (128->64->32, relu both) ----------------
__global__ __launch_bounds__(64) void k_head(const float* __restrict__ gsum, const float* __restrict__ gcnt,
    const float* __restrict__ W1, const float* __restrict__ b1,
    const float* __restrict__ W2, const float* __restrict__ b2, float* __restrict__ out){
  __shared__ float pooled[128];
  __shared__ float h1[64];
  int g = blockIdx.x, t = threadIdx.x;
  float cnt = fmaxf(gcnt[g], 1.f);
  pooled[t]      = gsum[g*128 + t] / cnt;
  pooled[t + 64] = gsum[g*128 + 64 + t] / cnt;
  __syncthreads();
  float a = b1[t];
  for (int k=0; k<128; k++) a = fmaf(pooled[k], W1[k*64 + t], a);
  h1[t] = fmaxf(a, 0.f);
  __syncthreads();
  if (t < 32){
    float o = b2[t];
    for (int k=0; k<64; k++) o = fmaf(h1[k], W2[k*32 + t], o);
    out[g*32 + t] = fmaxf(o, 0.f);
  }
}

extern "C" void kernel_launch(void* const* d_in, const int* in_sizes, int n_in,
                              void* d_out, int out_size, void* d_ws, size_t ws_size,
                              hipStream_t stream){
  const float* emb  = (const float*)d_in[0];
  const float* pose = (const float*)d_in[1];
  const int*   ei   = (const int*)d_in[2];
  const int*   batch= (const int*)d_in[3];
  const float* Wpre = (const float*)d_in[4];
  const float* bpre = (const float*)d_in[5];
  const float* Wg1  = (const float*)d_in[6];
  const float* bg1  = (const float*)d_in[7];
  const float* Wg2  = (const float*)d_in[8];
  const float* bg2  = (const float*)d_in[9];
  const float* Wh1  = (const float*)d_in[10];
  const float* bh1  = (const float*)d_in[11];
  const float* Wh2  = (const float*)d_in[12];
  const float* bh2  = (const float*)d_in[13];
  float* out = (float*)d_out;

  char* ws = (char*)d_ws;
  unsigned short* xb0 = (unsigned short*)(ws + 0);          // 12,800,000
  unsigned short* xb1 = (unsigned short*)(ws + 12800000);   // 12,800,000
  unsigned short* hb  = (unsigned short*)(ws + 25600000);   // 12,800,000
  unsigned short* Wt1 = (unsigned short*)(ws + 38400000);   // 32,768
  unsigned short* Wt2 = (unsigned short*)(ws + 38432768);   // 32,768
  int2*  sd   = (int2*) (ws + 38465536);   // 400,000
  float* dinv = (float*)(ws + 38865536);   // 200,000
  int*   ssrc = (int*)  (ws + 39065536);   // NBKT*CAP*4 = 4,804,608
  int2*  pairs= (int2*) (ws + 43870144);   // NBKT*CAP*8 = 9,609,216
  int*   bcnt = (int*)  (ws + 53479360);   // NBKT*16*4 = 50,048
  float* gsum = (float*)(ws + 53529408);   // 65,536
  float* gcnt = (float*)(ws + 53594944);   // 512

  hipMemsetAsync(bcnt, 0, NBKT*16*sizeof(int), stream);
  hipMemsetAsync(gsum, 0, (NG*128 + NG)*sizeof(float), stream);  // gsum + gcnt contiguous

  k_bucket<<<(N_E+255)/256, 256, 0, stream>>>(ei, bcnt, pairs);
  k_csr   <<<NBKT, 256, 0, stream>>>(pairs, bcnt, sd, dinv, ssrc);

  k_wt<<<64, 256, 0, stream>>>(Wg1, Wt1);
  k_wt<<<64, 256, 0, stream>>>(Wg2, Wt2);

  k_pre<<<(N_N+63)/64, 256, 0, stream>>>(emb, pose, Wpre, bpre, xb0);             // x1 -> xb0 (bf16)

  k_gemm_mfma<<<(N_N+127)/128, 256, 0, stream>>>(xb0, Wt1, dinv, hb);             // hs1 -> hb
  k_agg<<<N_N/4, 256, 0, stream>>>(hb, sd, ssrc, dinv, bg1, xb1);                 // x2 -> xb1

  k_gemm_mfma<<<(N_N+127)/128, 256, 0, stream>>>(xb1, Wt2, dinv, hb);             // hs2 -> hb
  k_agg<<<N_N/4, 256, 0, stream>>>(hb, sd, ssrc, dinv, bg2, xb0);                 // x3 -> xb0

  k_pool<<<(N_N+127)/128, 128, 0, stream>>>(xb0, batch, gsum, gcnt);
  k_head<<<NG, 64, 0, stream>>>(gsum, gcnt, Wh1, bh1, Wh2, bh2, out);
}

// Round 4
// 201.977 us; speedup vs baseline: 2.0148x; 1.1386x over previous
//
#include <hip/hip_runtime.h>

#define N_N 50000
#define N_E 800000
#define NG  128
#define NBKT 782          // ceil(50000/64) buckets of 64 nodes
#define CAP  1536         // slot capacity per bucket (mean 1023, sigma 32)
#define EPB  8192         // edges per k_bin block
#define BINB 98           // ceil(800000/8192)

typedef float4 f4;
typedef __attribute__((ext_vector_type(8))) short bf16x8;
typedef __attribute__((ext_vector_type(4))) float f32x4;

__device__ __forceinline__ unsigned short f2b(float x){
  unsigned int u = __float_as_uint(x);
  u += 0x7fffu + ((u >> 16) & 1u);
  return (unsigned short)(u >> 16);
}
__device__ __forceinline__ float b2f(unsigned short h){
  return __uint_as_float(((unsigned int)h) << 16);
}
__device__ __forceinline__ float2 b2f2(unsigned int u){
  float2 r;
  r.x = __uint_as_float(u << 16);
  r.y = __uint_as_float(u & 0xffff0000u);
  return r;
}

// ---------------- block-local counting sort into coarse buckets ----------------
// packs (src<<16 | dst) into u32 (both < 65536)
__global__ __launch_bounds__(512) void k_bin(const int* __restrict__ ei,
    int* __restrict__ bcnt, unsigned int* __restrict__ bins){
  __shared__ unsigned int sorted[EPB];   // 32 KB
  __shared__ int hist[NBKT];
  __shared__ int lstart[NBKT];
  __shared__ int lcur[NBKT];
  __shared__ int gbase[NBKT];
  __shared__ int segsum[16];
  int t = threadIdx.x;
  int e0 = blockIdx.x * EPB;
  int n = N_E - e0; if (n > EPB) n = EPB;
  for (int i=t; i<NBKT; i+=512) hist[i] = 0;
  __syncthreads();
  // pass 1: histogram by coarse bucket
  for (int i=t; i<n; i+=512){
    int d = ei[N_E + e0 + i];
    atomicAdd(&hist[d>>6], 1);
  }
  __syncthreads();
  // scan: 13 segments of 64, wave-scan each, then serial seg-offset fixup
  int w = t >> 6, lane = t & 63;
  for (int seg = w; seg < 13; seg += 8){
    int idx = seg*64 + lane;
    int v = (idx < NBKT) ? hist[idx] : 0;
    int x = v;
    #pragma unroll
    for (int dd=1; dd<64; dd<<=1){ int y = __shfl_up(x, dd, 64); if (lane >= dd) x += y; }
    if (idx < NBKT) lstart[idx] = x - v;
    if (lane == 63) segsum[seg] = x;
  }
  __syncthreads();
  if (t == 0){ int s=0; for (int j=0;j<13;j++){ int v=segsum[j]; segsum[j]=s; s+=v; } }
  __syncthreads();
  for (int i=t; i<NBKT; i+=512){ int v = lstart[i] + segsum[i>>6]; lstart[i] = v; lcur[i] = v; }
  __syncthreads();
  // pass 2: place into LDS, segment-ordered
  for (int i=t; i<n; i+=512){
    int s = ei[e0 + i], d = ei[N_E + e0 + i];
    int pos = atomicAdd(&lcur[d>>6], 1);
    sorted[pos] = ((unsigned int)s << 16) | (unsigned int)d;
  }
  __syncthreads();
  // reserve global segment space (one atomic per bucket per block)
  for (int i=t; i<NBKT; i+=512) gbase[i] = atomicAdd(&bcnt[i], hist[i]);
  __syncthreads();
  // pass 3: copy out, coalesced within segments
  for (int i=t; i<n; i+=512){
    unsigned int item = sorted[i];
    int d = item & 0xffff;
    int b = d >> 6;
    bins[b*CAP + gbase[b] + (i - lstart[b])] = item;
  }
}

// ---------------- per-bucket CSR finalize: hist -> scan -> place ----------------
__global__ __launch_bounds__(256) void k_csr(const unsigned int* __restrict__ bins,
    const int* __restrict__ bcnt, int2* __restrict__ sd, float* __restrict__ dinv,
    int* __restrict__ ssrc){
  __shared__ int hist[64];
  __shared__ int lcur[64];
  __shared__ int cnt_s;
  int b = blockIdx.x, t = threadIdx.x;
  if (t < 64) hist[t] = 0;
  if (t == 0) cnt_s = bcnt[b];
  __syncthreads();
  int cnt = cnt_s;
  const unsigned int* P = bins + b*CAP;
  for (int j=t; j<cnt; j+=256) atomicAdd(&hist[P[j] & 63], 1);
  __syncthreads();
  if (t < 64){
    int v = hist[t];
    int x = v;
    #pragma unroll
    for (int dd=1; dd<64; dd<<=1){ int y = __shfl_up(x, dd, 64); if (t >= dd) x += y; }
    int excl = x - v;
    int node = (b<<6) + t;
    if (node < N_N){
      sd[node] = make_int2(b*CAP + excl, v);
      dinv[node] = rsqrtf((float)(v + 1));    // +1 self-loop
    }
    lcur[t] = b*CAP + excl;
  }
  __syncthreads();
  for (int j=t; j<cnt; j+=256){
    unsigned int p = P[j];
    int pos = atomicAdd(&lcur[p & 63], 1);
    ssrc[pos] = (int)(p >> 16);
  }
}

// ---------------- W (fp32 [k][n]) -> Wt (bf16 [n][k]) ----------------
__global__ __launch_bounds__(256) void k_wt(const float* __restrict__ W, unsigned short* __restrict__ Wt){
  int i = blockIdx.x*256 + threadIdx.x;   // 16384
  int k = i >> 7, n = i & 127;
  Wt[n*128 + k] = f2b(W[k*128 + n]);
}

// ---------------- fused add + preprocess MLP (64->128, relu), bf16 out ----------------
__global__ __launch_bounds__(256) void k_pre(const float* __restrict__ emb, const float* __restrict__ pose,
    const float* __restrict__ W, const float* __restrict__ bias, unsigned short* __restrict__ out){
  __shared__ float As[64*64];
  __shared__ float Bs[64*128];
  int row0 = blockIdx.x*64, tid = threadIdx.x;
  for (int j=tid; j<2048; j+=256) ((f4*)Bs)[j] = ((const f4*)W)[j];
  for (int j=tid; j<1024; j+=256){
    int r = j>>4, c4 = j&15;
    int gr = row0 + r;
    f4 a = {0.f,0.f,0.f,0.f};
    if (gr < N_N){
      f4 e0 = ((const f4*)emb)[gr*16 + c4];
      f4 p0 = ((const f4*)pose)[gr*16 + c4];
      a.x = e0.x+p0.x; a.y = e0.y+p0.y; a.z = e0.z+p0.z; a.w = e0.w+p0.w;
    }
    ((f4*)As)[j] = a;
  }
  __syncthreads();
  int cg = tid&31, rg = tid>>5;
  float acc[8][4] = {};
  for (int k=0;k<64;k++){
    f4 b = ((f4*)Bs)[k*32 + cg];
    #pragma unroll
    for (int i=0;i<8;i++){
      float a = As[(rg*8+i)*64 + k];
      acc[i][0] = fmaf(a,b.x,acc[i][0]); acc[i][1] = fmaf(a,b.y,acc[i][1]);
      acc[i][2] = fmaf(a,b.z,acc[i][2]); acc[i][3] = fmaf(a,b.w,acc[i][3]);
    }
  }
  f4 bb = ((const f4*)bias)[cg];
  for (int i=0;i<8;i++){
    int gr = row0 + rg*8 + i;
    if (gr < N_N){
      ushort4 o;
      o.x = f2b(fmaxf(acc[i][0]+bb.x, 0.f));
      o.y = f2b(fmaxf(acc[i][1]+bb.y, 0.f));
      o.z = f2b(fmaxf(acc[i][2]+bb.z, 0.f));
      o.w = f2b(fmaxf(acc[i][3]+bb.w, 0.f));
      *(ushort4*)&out[gr*128 + cg*4] = o;
    }
  }
}

// ---------------- MFMA GEMM: hs = (A @ W) * dinv[row], A bf16 [M][128], Wt bf16 [n][k] ----------------
__global__ __launch_bounds__(256) void k_gemm_mfma(const unsigned short* __restrict__ A,
    const unsigned short* __restrict__ Wt, const float* __restrict__ scale,
    unsigned short* __restrict__ out){
  __shared__ unsigned short Bs[128*128];   // 32 KB, XOR-swizzled [n][k] tiles of 8 bf16
  int tid = threadIdx.x;
  for (int j=tid; j<2048; j+=256){
    int n = j >> 4, c = j & 15;
    ((bf16x8*)Bs)[(n<<4) | (c ^ (n&7))] = ((const bf16x8*)Wt)[j];
  }
  __syncthreads();
  int wid = tid >> 6, l = tid & 63;
  int row0 = blockIdx.x*128 + wid*32;
  int lr = l & 15, kg = l >> 4;
  int ra = row0 + lr;       if (ra > N_N-1) ra = N_N-1;
  int rb = row0 + 16 + lr;  if (rb > N_N-1) rb = N_N-1;
  f32x4 acc[2][8] = {};
  #pragma unroll
  for (int ks=0; ks<4; ks++){
    int k0 = ks*32 + kg*8;
    bf16x8 a0 = *(const bf16x8*)&A[ra*128 + k0];
    bf16x8 a1 = *(const bf16x8*)&A[rb*128 + k0];
    #pragma unroll
    for (int nf=0; nf<8; nf++){
      int n = nf*16 + lr;
      bf16x8 b = ((const bf16x8*)Bs)[(n<<4) | ((ks*4+kg) ^ (lr&7))];
      acc[0][nf] = __builtin_amdgcn_mfma_f32_16x16x32_bf16(a0, b, acc[0][nf], 0, 0, 0);
      acc[1][nf] = __builtin_amdgcn_mfma_f32_16x16x32_bf16(a1, b, acc[1][nf], 0, 0, 0);
    }
  }
  #pragma unroll
  for (int mf=0; mf<2; mf++){
    #pragma unroll
    for (int r=0; r<4; r++){
      int R = row0 + mf*16 + (l>>4)*4 + r;
      if (R < N_N){
        float s = scale[R];
        #pragma unroll
        for (int nf=0; nf<8; nf++){
          out[R*128 + nf*16 + lr] = f2b(acc[mf][nf][r] * s);
        }
      }
    }
  }
}

// ---------------- edge aggregation: out[v] = relu(dinv[v]*(hs[v] + sum hs[src]) + b), bf16 ----------------
__global__ __launch_bounds__(256) void k_agg(const unsigned short* __restrict__ hs,
    const int2* __restrict__ sd, const int* __restrict__ ssrc, const float* __restrict__ dinv,
    const float* __restrict__ bias, unsigned short* __restrict__ out){
  int v = blockIdx.x*4 + (threadIdx.x>>6);
  int l = threadIdx.x & 63;
  const unsigned int* h2 = (const unsigned int*)hs;   // 2 bf16 per uint
  float2 acc = b2f2(h2[(v<<6) + l]);                  // self-loop term hs[v]
  int2 s_d = sd[v];
  int s = s_d.x, e = s + s_d.y;
  int j = s;
  for (; j+8 <= e; j+=8){
    int u0 = ssrc[j],   u1 = ssrc[j+1], u2 = ssrc[j+2], u3 = ssrc[j+3];
    int u4 = ssrc[j+4], u5 = ssrc[j+5], u6 = ssrc[j+6], u7 = ssrc[j+7];
    unsigned int m0 = h2[(u0<<6)+l], m1 = h2[(u1<<6)+l];
    unsigned int m2 = h2[(u2<<6)+l], m3 = h2[(u3<<6)+l];
    unsigned int m4 = h2[(u4<<6)+l], m5 = h2[(u5<<6)+l];
    unsigned int m6 = h2[(u6<<6)+l], m7 = h2[(u7<<6)+l];
    float2 f0=b2f2(m0), f1=b2f2(m1), f2=b2f2(m2), f3=b2f2(m3);
    float2 f4_=b2f2(m4), f5=b2f2(m5), f6=b2f2(m6), f7=b2f2(m7);
    acc.x += ((f0.x+f1.x)+(f2.x+f3.x)) + ((f4_.x+f5.x)+(f6.x+f7.x));
    acc.y += ((f0.y+f1.y)+(f2.y+f3.y)) + ((f4_.y+f5.y)+(f6.y+f7.y));
  }
  for (; j<e; j++){
    float2 m = b2f2(h2[(ssrc[j]<<6)+l]);
    acc.x += m.x; acc.y += m.y;
  }
  float dv = dinv[v];
  float2 bb = ((const float2*)bias)[l];
  unsigned int o = (unsigned int)f2b(fmaxf(fmaf(dv, acc.x, bb.x), 0.f))
                 | ((unsigned int)f2b(fmaxf(fmaf(dv, acc.y, bb.y), 0.f)) << 16);
  ((unsigned int*)out)[(v<<6) + l] = o;
}

// ---------------- mean pool over sorted batch (bf16 in) ----------------
__global__ __launch_bounds__(128) void k_pool(const unsigned short* __restrict__ x, const int* __restrict__ batch,
    float* __restrict__ gsum, float* __restrict__ gcnt){
  int c = threadIdx.x;
  int n0 = blockIdx.x*128;
  int n1 = n0 + 128; if (n1 > N_N) n1 = N_N;
  int cur = batch[n0];
  float acc = 0.f, cnt = 0.f;
  for (int i=n0; i<n1; i++){
    int b = batch[i];
    if (b != cur){
      atomicAdd(&gsum[cur*128+c], acc);
      if (c == 0) atomicAdd(&gcnt[cur], cnt);
      acc = 0.f; cnt = 0.f; cur = b;
    }
    acc += b2f(x[i*128+c]);
    cnt += 1.f;
  }
  atomicAdd(&gsum[cur*128+c], acc);
  if (c == 0) atomicAdd(&gcnt[cur], cnt);
}

// ---------------- head MLP (128->64->32, relu both) ----------------
__global__ __launch_bounds__(64) void k_head(const float* __restrict__ gsum, const float* __restrict__ gcnt,
    const float* __restrict__ W1, const float* __restrict__ b1,
    const float* __restrict__ W2, const float* __restrict__ b2, float* __restrict__ out){
  __shared__ float pooled[128];
  __shared__ float h1[64];
  int g = blockIdx.x, t = threadIdx.x;
  float cnt = fmaxf(gcnt[g], 1.f);
  pooled[t]      = gsum[g*128 + t] / cnt;
  pooled[t + 64] = gsum[g*128 + 64 + t] / cnt;
  __syncthreads();
  float a = b1[t];
  for (int k=0; k<128; k++) a = fmaf(pooled[k], W1[k*64 + t], a);
  h1[t] = fmaxf(a, 0.f);
  __syncthreads();
  if (t < 32){
    float o = b2[t];
    for (int k=0; k<64; k++) o = fmaf(h1[k], W2[k*32 + t], o);
    out[g*32 + t] = fmaxf(o, 0.f);
  }
}

extern "C" void kernel_launch(void* const* d_in, const int* in_sizes, int n_in,
                              void* d_out, int out_size, void* d_ws, size_t ws_size,
                              hipStream_t stream){
  const float* emb  = (const float*)d_in[0];
  const float* pose = (const float*)d_in[1];
  const int*   ei   = (const int*)d_in[2];
  const int*   batch= (const int*)d_in[3];
  const float* Wpre = (const float*)d_in[4];
  const float* bpre = (const float*)d_in[5];
  const float* Wg1  = (const float*)d_in[6];
  const float* bg1  = (const float*)d_in[7];
  const float* Wg2  = (const float*)d_in[8];
  const float* bg2  = (const float*)d_in[9];
  const float* Wh1  = (const float*)d_in[10];
  const float* bh1  = (const float*)d_in[11];
  const float* Wh2  = (const float*)d_in[12];
  const float* bh2  = (const float*)d_in[13];
  float* out = (float*)d_out;

  char* ws = (char*)d_ws;
  unsigned short* xb0 = (unsigned short*)(ws + 0);          // 12,800,000
  unsigned short* xb1 = (unsigned short*)(ws + 12800000);   // 12,800,000
  unsigned short* hb  = (unsigned short*)(ws + 25600000);   // 12,800,000
  unsigned short* Wt1 = (unsigned short*)(ws + 38400000);   // 32,768
  unsigned short* Wt2 = (unsigned short*)(ws + 38432768);   // 32,768
  int2*  sd   = (int2*) (ws + 38465536);   // 400,000
  float* dinv = (float*)(ws + 38865536);   // 200,000
  int*   ssrc = (int*)  (ws + 39065536);   // NBKT*CAP*4 = 4,804,608
  unsigned int* bins = (unsigned int*)(ws + 43870144);   // NBKT*CAP*4 = 4,804,608
  int*   bcnt = (int*)  (ws + 48674752);   // NBKT*4 = 3,128
  float* gsum = (float*)(ws + 48677888);   // 65,536
  float* gcnt = (float*)(ws + 48743424);   // 512

  hipMemsetAsync(bcnt, 0, NBKT*sizeof(int), stream);
  hipMemsetAsync(gsum, 0, (NG*128 + NG)*sizeof(float), stream);  // gsum + gcnt contiguous

  k_bin<<<BINB, 512, 0, stream>>>(ei, bcnt, bins);
  k_csr<<<NBKT, 256, 0, stream>>>(bins, bcnt, sd, dinv, ssrc);

  k_wt<<<64, 256, 0, stream>>>(Wg1, Wt1);
  k_wt<<<64, 256, 0, stream>>>(Wg2, Wt2);

  k_pre<<<(N_N+63)/64, 256, 0, stream>>>(emb, pose, Wpre, bpre, xb0);             // x1 -> xb0 (bf16)

  k_gemm_mfma<<<(N_N+127)/128, 256, 0, stream>>>(xb0, Wt1, dinv, hb);             // hs1 -> hb
  k_agg<<<N_N/4, 256, 0, stream>>>(hb, sd, ssrc, dinv, bg1, xb1);                 // x2 -> xb1

  k_gemm_mfma<<<(N_N+127)/128, 256, 0, stream>>>(xb1, Wt2, dinv, hb);             // hs2 -> hb
  k_agg<<<N_N/4, 256, 0, stream>>>(hb, sd, ssrc, dinv, bg2, xb0);                 // x3 -> xb0

  k_pool<<<(N_N+127)/128, 128, 0, stream>>>(xb0, batch, gsum, gcnt);
  k_head<<<NG, 64, 0, stream>>>(gsum, gcnt, Wh1, bh1, Wh2, bh2, out);
}

// Round 8
// 195.888 us; speedup vs baseline: 2.0774x; 1.0311x over previous
//
#include <hip/hip_runtime.h>

#define N_N 50000
#define N_E 800000
#define NG  128
#define NBKT 782          // ceil(50000/64) buckets of 64 nodes
#define CAP  1536         // slot capacity per bucket (mean 1023, sigma 32)
#define EPB  8192         // edges per k_bin block
#define BINB 98           // ceil(800000/8192)

typedef float4 f4;
typedef __attribute__((ext_vector_type(8))) short bf16x8;
typedef __attribute__((ext_vector_type(4))) float f32x4;

__device__ __forceinline__ unsigned short f2b(float x){
  unsigned int u = __float_as_uint(x);
  u += 0x7fffu + ((u >> 16) & 1u);
  return (unsigned short)(u >> 16);
}
__device__ __forceinline__ float b2f(unsigned short h){
  return __uint_as_float(((unsigned int)h) << 16);
}
__device__ __forceinline__ float2 b2f2(unsigned int u){
  float2 r;
  r.x = __uint_as_float(u << 16);
  r.y = __uint_as_float(u & 0xffff0000u);
  return r;
}

// ---------------- zero scratch counters (replaces 2x hipMemsetAsync ~43us each) ----------------
// zeros bcnt (NBKT ints) + gsum (NG*128 floats) + gcnt (NG floats), laid out contiguously
__global__ __launch_bounds__(256) void k_zero(int* __restrict__ p, int n4){
  int i = blockIdx.x*256 + threadIdx.x;
  if (i < n4) p[i] = 0;
}

// ---------------- block-local counting sort into coarse buckets ----------------
// packs (src<<16 | dst) into u32 (both < 65536)
__global__ __launch_bounds__(512) void k_bin(const int* __restrict__ ei,
    int* __restrict__ bcnt, unsigned int* __restrict__ bins){
  __shared__ unsigned int sorted[EPB];   // 32 KB
  __shared__ int hist[NBKT];
  __shared__ int lstart[NBKT];
  __shared__ int lcur[NBKT];
  __shared__ int gbase[NBKT];
  __shared__ int segsum[16];
  int t = threadIdx.x;
  int e0 = blockIdx.x * EPB;
  int n = N_E - e0; if (n > EPB) n = EPB;
  for (int i=t; i<NBKT; i+=512) hist[i] = 0;
  __syncthreads();
  for (int i=t; i<n; i+=512){
    int d = ei[N_E + e0 + i];
    atomicAdd(&hist[d>>6], 1);
  }
  __syncthreads();
  int w = t >> 6, lane = t & 63;
  for (int seg = w; seg < 13; seg += 8){
    int idx = seg*64 + lane;
    int v = (idx < NBKT) ? hist[idx] : 0;
    int x = v;
    #pragma unroll
    for (int dd=1; dd<64; dd<<=1){ int y = __shfl_up(x, dd, 64); if (lane >= dd) x += y; }
    if (idx < NBKT) lstart[idx] = x - v;
    if (lane == 63) segsum[seg] = x;
  }
  __syncthreads();
  if (t == 0){ int s=0; for (int j=0;j<13;j++){ int v=segsum[j]; segsum[j]=s; s+=v; } }
  __syncthreads();
  for (int i=t; i<NBKT; i+=512){ int v = lstart[i] + segsum[i>>6]; lstart[i] = v; lcur[i] = v; }
  __syncthreads();
  for (int i=t; i<n; i+=512){
    int s = ei[e0 + i], d = ei[N_E + e0 + i];
    int pos = atomicAdd(&lcur[d>>6], 1);
    sorted[pos] = ((unsigned int)s << 16) | (unsigned int)d;
  }
  __syncthreads();
  for (int i=t; i<NBKT; i+=512) gbase[i] = atomicAdd(&bcnt[i], hist[i]);
  __syncthreads();
  for (int i=t; i<n; i+=512){
    unsigned int item = sorted[i];
    int d = item & 0xffff;
    int b = d >> 6;
    bins[b*CAP + gbase[b] + (i - lstart[b])] = item;
  }
}

// ---------------- per-bucket CSR finalize: hist -> scan -> place ----------------
__global__ __launch_bounds__(256) void k_csr(const unsigned int* __restrict__ bins,
    const int* __restrict__ bcnt, int2* __restrict__ sd, float* __restrict__ dinv,
    int* __restrict__ ssrc){
  __shared__ int hist[64];
  __shared__ int lcur[64];
  __shared__ int cnt_s;
  int b = blockIdx.x, t = threadIdx.x;
  if (t < 64) hist[t] = 0;
  if (t == 0) cnt_s = bcnt[b];
  __syncthreads();
  int cnt = cnt_s;
  const unsigned int* P = bins + b*CAP;
  for (int j=t; j<cnt; j+=256) atomicAdd(&hist[P[j] & 63], 1);
  __syncthreads();
  if (t < 64){
    int v = hist[t];
    int x = v;
    #pragma unroll
    for (int dd=1; dd<64; dd<<=1){ int y = __shfl_up(x, dd, 64); if (t >= dd) x += y; }
    int excl = x - v;
    int node = (b<<6) + t;
    if (node < N_N){
      sd[node] = make_int2(b*CAP + excl, v);
      dinv[node] = rsqrtf((float)(v + 1));    // +1 self-loop
    }
    lcur[t] = b*CAP + excl;
  }
  __syncthreads();
  for (int j=t; j<cnt; j+=256){
    unsigned int p = P[j];
    int pos = atomicAdd(&lcur[p & 63], 1);
    ssrc[pos] = (int)(p >> 16);
  }
}

// ---------------- W (fp32 [k][n]) -> Wt (bf16 [n][k]), both weights in one launch ----------------
__global__ __launch_bounds__(256) void k_wt(const float* __restrict__ W1, const float* __restrict__ W2,
    unsigned short* __restrict__ Wt1, unsigned short* __restrict__ Wt2){
  int i = blockIdx.x*256 + threadIdx.x;   // 32768
  const float* W = (i < 16384) ? W1 : W2;
  unsigned short* Wt = (i < 16384) ? Wt1 : Wt2;
  int j = i & 16383;
  int k = j >> 7, n = j & 127;
  Wt[n*128 + k] = f2b(W[k*128 + n]);
}

// ---------------- fused add + preprocess MLP (64->128, relu), bf16 out ----------------
__global__ __launch_bounds__(256) void k_pre(const float* __restrict__ emb, const float* __restrict__ pose,
    const float* __restrict__ W, const float* __restrict__ bias, unsigned short* __restrict__ out){
  __shared__ float As[64*64];
  __shared__ float Bs[64*128];
  int row0 = blockIdx.x*64, tid = threadIdx.x;
  for (int j=tid; j<2048; j+=256) ((f4*)Bs)[j] = ((const f4*)W)[j];
  for (int j=tid; j<1024; j+=256){
    int r = j>>4, c4 = j&15;
    int gr = row0 + r;
    f4 a = {0.f,0.f,0.f,0.f};
    if (gr < N_N){
      f4 e0 = ((const f4*)emb)[gr*16 + c4];
      f4 p0 = ((const f4*)pose)[gr*16 + c4];
      a.x = e0.x+p0.x; a.y = e0.y+p0.y; a.z = e0.z+p0.z; a.w = e0.w+p0.w;
    }
    ((f4*)As)[j] = a;
  }
  __syncthreads();
  int cg = tid&31, rg = tid>>5;
  float acc[8][4] = {};
  for (int k=0;k<64;k++){
    f4 b = ((f4*)Bs)[k*32 + cg];
    #pragma unroll
    for (int i=0;i<8;i++){
      float a = As[(rg*8+i)*64 + k];
      acc[i][0] = fmaf(a,b.x,acc[i][0]); acc[i][1] = fmaf(a,b.y,acc[i][1]);
      acc[i][2] = fmaf(a,b.z,acc[i][2]); acc[i][3] = fmaf(a,b.w,acc[i][3]);
    }
  }
  f4 bb = ((const f4*)bias)[cg];
  for (int i=0;i<8;i++){
    int gr = row0 + rg*8 + i;
    if (gr < N_N){
      ushort4 o;
      o.x = f2b(fmaxf(acc[i][0]+bb.x, 0.f));
      o.y = f2b(fmaxf(acc[i][1]+bb.y, 0.f));
      o.z = f2b(fmaxf(acc[i][2]+bb.z, 0.f));
      o.w = f2b(fmaxf(acc[i][3]+bb.w, 0.f));
      *(ushort4*)&out[gr*128 + cg*4] = o;
    }
  }
}

// ---------------- MFMA GEMM: hs = (A @ W) * dinv[row], A bf16 [M][128], Wt bf16 [n][k] ----------------
__global__ __launch_bounds__(256) void k_gemm_mfma(const unsigned short* __restrict__ A,
    const unsigned short* __restrict__ Wt, const float* __restrict__ scale,
    unsigned short* __restrict__ out){
  __shared__ unsigned short Bs[128*128];   // 32 KB, XOR-swizzled [n][k] tiles of 8 bf16
  int tid = threadIdx.x;
  for (int j=tid; j<2048; j+=256){
    int n = j >> 4, c = j & 15;
    ((bf16x8*)Bs)[(n<<4) | (c ^ (n&7))] = ((const bf16x8*)Wt)[j];
  }
  __syncthreads();
  int wid = tid >> 6, l = tid & 63;
  int row0 = blockIdx.x*128 + wid*32;
  int lr = l & 15, kg = l >> 4;
  int ra = row0 + lr;       if (ra > N_N-1) ra = N_N-1;
  int rb = row0 + 16 + lr;  if (rb > N_N-1) rb = N_N-1;
  f32x4 acc[2][8] = {};
  #pragma unroll
  for (int ks=0; ks<4; ks++){
    int k0 = ks*32 + kg*8;
    bf16x8 a0 = *(const bf16x8*)&A[ra*128 + k0];
    bf16x8 a1 = *(const bf16x8*)&A[rb*128 + k0];
    #pragma unroll
    for (int nf=0; nf<8; nf++){
      int n = nf*16 + lr;
      bf16x8 b = ((const bf16x8*)Bs)[(n<<4) | ((ks*4+kg) ^ (lr&7))];
      acc[0][nf] = __builtin_amdgcn_mfma_f32_16x16x32_bf16(a0, b, acc[0][nf], 0, 0, 0);
      acc[1][nf] = __builtin_amdgcn_mfma_f32_16x16x32_bf16(a1, b, acc[1][nf], 0, 0, 0);
    }
  }
  #pragma unroll
  for (int mf=0; mf<2; mf++){
    #pragma unroll
    for (int r=0; r<4; r++){
      int R = row0 + mf*16 + (l>>4)*4 + r;
      if (R < N_N){
        float s = scale[R];
        #pragma unroll
        for (int nf=0; nf<8; nf++){
          out[R*128 + nf*16 + lr] = f2b(acc[mf][nf][r] * s);
        }
      }
    }
  }
}

// ---------------- edge aggregation: out[v] = relu(dinv[v]*(hs[v] + sum hs[src]) + b), bf16 ----------------
__global__ __launch_bounds__(256) void k_agg(const unsigned short* __restrict__ hs,
    const int2* __restrict__ sd, const int* __restrict__ ssrc, const float* __restrict__ dinv,
    const float* __restrict__ bias, unsigned short* __restrict__ out){
  int v = blockIdx.x*4 + (threadIdx.x>>6);
  int l = threadIdx.x & 63;
  const unsigned int* h2 = (const unsigned int*)hs;   // 2 bf16 per uint
  float2 acc = b2f2(h2[(v<<6) + l]);                  // self-loop term hs[v]
  int2 s_d = sd[v];
  int s = s_d.x, e = s + s_d.y;
  int j = s;
  for (; j+8 <= e; j+=8){
    int u0 = ssrc[j],   u1 = ssrc[j+1], u2 = ssrc[j+2], u3 = ssrc[j+3];
    int u4 = ssrc[j+4], u5 = ssrc[j+5], u6 = ssrc[j+6], u7 = ssrc[j+7];
    unsigned int m0 = h2[(u0<<6)+l], m1 = h2[(u1<<6)+l];
    unsigned int m2 = h2[(u2<<6)+l], m3 = h2[(u3<<6)+l];
    unsigned int m4 = h2[(u4<<6)+l], m5 = h2[(u5<<6)+l];
    unsigned int m6 = h2[(u6<<6)+l], m7 = h2[(u7<<6)+l];
    float2 f0=b2f2(m0), f1=b2f2(m1), f2=b2f2(m2), f3=b2f2(m3);
    float2 f4_=b2f2(m4), f5=b2f2(m5), f6=b2f2(m6), f7=b2f2(m7);
    acc.x += ((f0.x+f1.x)+(f2.x+f3.x)) + ((f4_.x+f5.x)+(f6.x+f7.x));
    acc.y += ((f0.y+f1.y)+(f2.y+f3.y)) + ((f4_.y+f5.y)+(f6.y+f7.y));
  }
  for (; j<e; j++){
    float2 m = b2f2(h2[(ssrc[j]<<6)+l]);
    acc.x += m.x; acc.y += m.y;
  }
  float dv = dinv[v];
  float2 bb = ((const float2*)bias)[l];
  unsigned int o = (unsigned int)f2b(fmaxf(fmaf(dv, acc.x, bb.x), 0.f))
                 | ((unsigned int)f2b(fmaxf(fmaf(dv, acc.y, bb.y), 0.f)) << 16);
  ((unsigned int*)out)[(v<<6) + l] = o;
}

// ---------------- mean pool over sorted batch (bf16 in) ----------------
__global__ __launch_bounds__(128) void k_pool(const unsigned short* __restrict__ x, const int* __restrict__ batch,
    float* __restrict__ gsum, float* __restrict__ gcnt){
  int c = threadIdx.x;
  int n0 = blockIdx.x*128;
  int n1 = n0 + 128; if (n1 > N_N) n1 = N_N;
  int cur = batch[n0];
  float acc = 0.f, cnt = 0.f;
  for (int i=n0; i<n1; i++){
    int b = batch[i];
    if (b != cur){
      atomicAdd(&gsum[cur*128+c], acc);
      if (c == 0) atomicAdd(&gcnt[cur], cnt);
      acc = 0.f; cnt = 0.f; cur = b;
    }
    acc += b2f(x[i*128+c]);
    cnt += 1.f;
  }
  atomicAdd(&gsum[cur*128+c], acc);
  if (c == 0) atomicAdd(&gcnt[cur], cnt);
}

// ---------------- head MLP (128->64->32, relu both) ----------------
__global__ __launch_bounds__(64) void k_head(const float* __restrict__ gsum, const float* __restrict__ gcnt,
    const float* __restrict__ W1, const float* __restrict__ b1,
    const float* __restrict__ W2, const float* __restrict__ b2, float* __restrict__ out){
  __shared__ float pooled[128];
  __shared__ float h1[64];
  int g = blockIdx.x, t = threadIdx.x;
  float cnt = fmaxf(gcnt[g], 1.f);
  pooled[t]      = gsum[g*128 + t] / cnt;
  pooled[t + 64] = gsum[g*128 + 64 + t] / cnt;
  __syncthreads();
  float a = b1[t];
  for (int k=0; k<128; k++) a = fmaf(pooled[k], W1[k*64 + t], a);
  h1[t] = fmaxf(a, 0.f);
  __syncthreads();
  if (t < 32){
    float o = b2[t];
    for (int k=0; k<64; k++) o = fmaf(h1[k], W2[k*32 + t], o);
    out[g*32 + t] = fmaxf(o, 0.f);
  }
}

extern "C" void kernel_launch(void* const* d_in, const int* in_sizes, int n_in,
                              void* d_out, int out_size, void* d_ws, size_t ws_size,
                              hipStream_t stream){
  const float* emb  = (const float*)d_in[0];
  const float* pose = (const float*)d_in[1];
  const int*   ei   = (const int*)d_in[2];
  const int*   batch= (const int*)d_in[3];
  const float* Wpre = (const float*)d_in[4];
  const float* bpre = (const float*)d_in[5];
  const float* Wg1  = (const float*)d_in[6];
  const float* bg1  = (const float*)d_in[7];
  const float* Wg2  = (const float*)d_in[8];
  const float* bg2  = (const float*)d_in[9];
  const float* Wh1  = (const float*)d_in[10];
  const float* bh1  = (const float*)d_in[11];
  const float* Wh2  = (const float*)d_in[12];
  const float* bh2  = (const float*)d_in[13];
  float* out = (float*)d_out;

  char* ws = (char*)d_ws;
  unsigned short* xb0 = (unsigned short*)(ws + 0);          // 12,800,000
  unsigned short* xb1 = (unsigned short*)(ws + 12800000);   // 12,800,000
  unsigned short* hb  = (unsigned short*)(ws + 25600000);   // 12,800,000
  unsigned short* Wt1 = (unsigned short*)(ws + 38400000);   // 32,768
  unsigned short* Wt2 = (unsigned short*)(ws + 38432768);   // 32,768
  int2*  sd   = (int2*) (ws + 38465536);   // 400,000
  float* dinv = (float*)(ws + 38865536);   // 200,000
  int*   ssrc = (int*)  (ws + 39065536);   // NBKT*CAP*4 = 4,804,608
  unsigned int* bins = (unsigned int*)(ws + 43870144);   // NBKT*CAP*4 = 4,804,608
  // contiguous zero region: bcnt | gsum | gcnt
  int*   bcnt = (int*)  (ws + 48674752);   // NBKT*4 = 3,128 (pad to 3,136)
  float* gsum = (float*)(ws + 48677888);   // 65,536
  float* gcnt = (float*)(ws + 48743424);   // 512

  const int ZN = (3136 + 65536 + 512) / 4;   // 17,296 ints
  k_zero<<<(ZN+255)/256, 256, 0, stream>>>(bcnt, ZN);

  k_bin<<<BINB, 512, 0, stream>>>(ei, bcnt, bins);
  k_csr<<<NBKT, 256, 0, stream>>>(bins, bcnt, sd, dinv, ssrc);

  k_wt<<<128, 256, 0, stream>>>(Wg1, Wg2, Wt1, Wt2);

  k_pre<<<(N_N+63)/64, 256, 0, stream>>>(emb, pose, Wpre, bpre, xb0);             // x1 -> xb0 (bf16)

  k_gemm_mfma<<<(N_N+127)/128, 256, 0, stream>>>(xb0, Wt1, dinv, hb);             // hs1 -> hb
  k_agg<<<N_N/4, 256, 0, stream>>>(hb, sd, ssrc, dinv, bg1, xb1);                 // x2 -> xb1

  k_gemm_mfma<<<(N_N+127)/128, 256, 0, stream>>>(xb1, Wt2, dinv, hb);             // hs2 -> hb
  k_agg<<<N_N/4, 256, 0, stream>>>(hb, sd, ssrc, dinv, bg2, xb0);                 // x3 -> xb0

  k_pool<<<(N_N+127)/128, 128, 0, stream>>>(xb0, batch, gsum, gcnt);
  k_head<<<NG, 64, 0, stream>>>(gsum, gcnt, Wh1, bh1, Wh2, bh2, out);
}